// Round 9
// baseline (201.622 us; speedup 1.0000x reference)
//
#include <hip/hip_runtime.h>
#include <math.h>

#define N_NODES 20000
#define N_EDGES 320000
#define IN_F 256
#define OUT_F 64
#define HEADS 4
#define NCOL 256            // HEADS*OUT_F
#define LRELU_ALPHA 0.1f
#define ELL_CAP 64          // max degree capacity; P(overflow) < 1e-13

#define SCAT_X 313                         // scatter blocks per y (512 thr, 1 edge/thread)
#define GEMM_GB 157                        // ceil(1250 row-groups / 8 waves)
#define CST_STRIDE 136                     // shorts per staged C row
#define AGG_BLOCKS 40000                   // 8 (dir,head) slices x 5000 node-quads

typedef __attribute__((ext_vector_type(8))) short short8;
typedef __attribute__((ext_vector_type(4))) float floatx4;

__device__ __forceinline__ float lrelu(float x) {
    return x > 0.f ? x : LRELU_ALPHA * x;
}
__device__ __forceinline__ unsigned short f2bf(float f) {   // RNE f32->bf16
    unsigned int u = __float_as_uint(f);
    u = (u + 0x7FFF + ((u >> 16) & 1)) >> 16;
    return (unsigned short)u;
}
__device__ __forceinline__ float bf2f(unsigned short u) {
    return __uint_as_float(((unsigned int)u) << 16);
}

// ---------------------------------------------------------------------------
// prep_w (64 blocks x 256)  [verified r0-r8, byte-identical]
// ---------------------------------------------------------------------------
__global__ __launch_bounds__(256) void prep_w_kernel(
    const float* __restrict__ Ws, const float* __restrict__ Wt,
    unsigned short* __restrict__ Wsb, unsigned short* __restrict__ Wtb,
    int* __restrict__ cnt)   // cnt_t followed by cnt_s
{
    const int gid = blockIdx.x * 256 + threadIdx.x;   // [0, 16384)

    for (int i = gid; i < 2 * N_NODES; i += 16384) cnt[i] = 0;

    const int mat = gid >> 13;
    const int r   = gid & 8191;
    const int kc  = r >> 8;          // 0..31 (k-octet)
    const int c   = r & 255;
    const float* W    = mat ? Wt : Ws;
    unsigned short* O = mat ? Wtb : Wsb;
    const int h = c >> 6, j = c & 63;
    const int k0 = kc * 8;
    unsigned short v[8] __attribute__((aligned(16)));
#pragma unroll
    for (int i = 0; i < 8; ++i)
        v[i] = f2bf(W[(size_t)h * (IN_F * OUT_F) + (size_t)(k0 + i) * OUT_F + j]);
    *(uint4*)(O + (size_t)c * IN_F + k0) = *(const uint4*)v;
}

// ---------------------------------------------------------------------------
// hybrid: scatter + half-W-resident GEMM + fused dots + LDS-staged C write.
// [verified r8, byte-identical]
// ---------------------------------------------------------------------------
__global__ __launch_bounds__(512, 4) void hybrid_kernel(
    const float* __restrict__ A0, const unsigned short* __restrict__ Wb0,
    const float* __restrict__ A1, const unsigned short* __restrict__ Wb1,
    unsigned short* __restrict__ C0, unsigned short* __restrict__ C1,
    const float* __restrict__ a1, const float* __restrict__ a2,
    float* __restrict__ ss1, float* __restrict__ ss2,
    float* __restrict__ tt1, float* __restrict__ tt2,
    const int* __restrict__ src, const int* __restrict__ tgt,
    int* __restrict__ cnt_t, int* __restrict__ cnt_s,
    unsigned short* __restrict__ elist_t, unsigned short* __restrict__ elist_s)
{
    const int tid = threadIdx.x;

    __shared__ __align__(16) unsigned short Bl[128][264];   // 67,584 B

    if (blockIdx.x < SCAT_X) {
        // ---- scatter: one edge per thread ----
        const int e = ((int)blockIdx.y * SCAT_X + (int)blockIdx.x) * 512 + tid;
        if (e < N_EDGES) {
            const int s = src[e], t = tgt[e];
            const int p = atomicAdd(&cnt_t[t], 1);
            const int q = atomicAdd(&cnt_s[s], 1);
            if (p < ELL_CAP) elist_t[t * ELL_CAP + p] = (unsigned short)s;
            if (q < ELL_CAP) elist_s[s * ELL_CAP + q] = (unsigned short)t;
        }
        return;
    }

    // ---- GEMM + fused dots ----
    const int gx   = blockIdx.x - SCAT_X;
    const int half = gx & 1;
    const int gb   = gx >> 1;             // 0..156
    const float* A           = (blockIdx.y == 0) ? A0 : A1;
    const unsigned short* Wb = (blockIdx.y == 0) ? Wb0 : Wb1;
    unsigned short* C        = (blockIdx.y == 0) ? C0 : C1;

    for (int i = tid; i < 4096; i += 512) {
        const int n  = i >> 5;            // 0..127
        const int kc = (i & 31) << 3;     // k-offset in shorts
        *(uint4*)&Bl[n][kc] = *(const uint4*)(Wb + (size_t)(half * 128 + n) * IN_F + kc);
    }
    __syncthreads();

    const int lane = tid & 63;
    const int w    = tid >> 6;            // wave 0..7
    const int quad = lane >> 4;
    const int l15  = lane & 15;
    const int g    = gb * 8 + w;          // row group 0..1255
    const bool live = (g < 1250);

    floatx4 acc[8];
#pragma unroll
    for (int c = 0; c < 8; ++c) acc[c] = (floatx4){0.f, 0.f, 0.f, 0.f};

    if (live) {
        const float* arow = A + (size_t)(g * 16 + l15) * IN_F + quad * 8;

        // batch 1: kk = 0..3
        float4 ua[8];
#pragma unroll
        for (int kk = 0; kk < 4; ++kk) {
            ua[2 * kk]     = *(const float4*)(arow + kk * 32);
            ua[2 * kk + 1] = *(const float4*)(arow + kk * 32 + 4);
        }
        short8 af[4];
#pragma unroll
        for (int kk = 0; kk < 4; ++kk) {
            short8 t;
            t[0] = (short)f2bf(ua[2 * kk].x);     t[1] = (short)f2bf(ua[2 * kk].y);
            t[2] = (short)f2bf(ua[2 * kk].z);     t[3] = (short)f2bf(ua[2 * kk].w);
            t[4] = (short)f2bf(ua[2 * kk + 1].x); t[5] = (short)f2bf(ua[2 * kk + 1].y);
            t[6] = (short)f2bf(ua[2 * kk + 1].z); t[7] = (short)f2bf(ua[2 * kk + 1].w);
            af[kk] = t;
        }

        // batch 2 loads fly under batch-1 MFMAs
        float4 ub[8];
#pragma unroll
        for (int kk = 0; kk < 4; ++kk) {
            ub[2 * kk]     = *(const float4*)(arow + (kk + 4) * 32);
            ub[2 * kk + 1] = *(const float4*)(arow + (kk + 4) * 32 + 4);
        }

#pragma unroll
        for (int kk = 0; kk < 4; ++kk) {
#pragma unroll
            for (int c = 0; c < 8; ++c) {
                short8 bfrag = *(const short8*)&Bl[c * 16 + l15][kk * 32 + quad * 8];
                acc[c] = __builtin_amdgcn_mfma_f32_16x16x32_bf16(af[kk], bfrag, acc[c], 0, 0, 0);
            }
        }

#pragma unroll
        for (int kk = 0; kk < 4; ++kk) {
            short8 t;
            t[0] = (short)f2bf(ub[2 * kk].x);     t[1] = (short)f2bf(ub[2 * kk].y);
            t[2] = (short)f2bf(ub[2 * kk].z);     t[3] = (short)f2bf(ub[2 * kk].w);
            t[4] = (short)f2bf(ub[2 * kk + 1].x); t[5] = (short)f2bf(ub[2 * kk + 1].y);
            t[6] = (short)f2bf(ub[2 * kk + 1].z); t[7] = (short)f2bf(ub[2 * kk + 1].w);
            af[kk] = t;
        }
#pragma unroll
        for (int kk = 0; kk < 4; ++kk) {
#pragma unroll
            for (int c = 0; c < 8; ++c) {
                short8 bfrag = *(const short8*)&Bl[c * 16 + l15][(kk + 4) * 32 + quad * 8];
                acc[c] = __builtin_amdgcn_mfma_f32_16x16x32_bf16(af[kk], bfrag, acc[c], 0, 0, 0);
            }
        }

        // ---- fused dots (register-only; before barriers) ----
        const int off_aj = (blockIdx.y == 0) ? 0 : 64;
        float* o1 = (blockIdx.y == 0) ? ss1 : tt1;
        float* o2 = (blockIdx.y == 0) ? ss2 : tt2;

        float p1[2][4] = {{0.f,0.f,0.f,0.f},{0.f,0.f,0.f,0.f}};
        float p2[2][4] = {{0.f,0.f,0.f,0.f},{0.f,0.f,0.f,0.f}};
#pragma unroll
        for (int c = 0; c < 8; ++c) {
            const int hl = c >> 2;                       // local head 0..1
            const int hh = half * 2 + hl;
            const int jj = (c & 3) * 16 + l15;
            const float w1 = a1[hh * 128 + off_aj + jj];
            const float w2 = a2[hh * 128 + off_aj + jj];
#pragma unroll
            for (int r = 0; r < 4; ++r) {
                p1[hl][r] += acc[c][r] * w1;
                p2[hl][r] += acc[c][r] * w2;
            }
        }
#pragma unroll
        for (int m = 1; m < 16; m <<= 1) {
#pragma unroll
            for (int hl = 0; hl < 2; ++hl)
#pragma unroll
                for (int r = 0; r < 4; ++r) {
                    p1[hl][r] += __shfl_xor(p1[hl][r], m, 64);
                    p2[hl][r] += __shfl_xor(p2[hl][r], m, 64);
                }
        }
        if (l15 == 0) {
#pragma unroll
            for (int r = 0; r < 4; ++r) {
                const int m = g * 16 + quad * 4 + r;
#pragma unroll
                for (int hl = 0; hl < 2; ++hl) {
                    const int hh = half * 2 + hl;
                    o1[m * HEADS + hh] = p1[hl][r];
                    o2[m * HEADS + hh] = p2[hl][r];
                }
            }
        }
    }

    // ---- C write via LDS staging: full-line writebacks only ----
    __syncthreads();                       // all waves done reading Bl
    unsigned short* Cst = &Bl[0][0];       // reuse as [128][CST_STRIDE]

    if (live) {
#pragma unroll
        for (int c = 0; c < 8; ++c) {
            const int lc = c * 16 + l15;               // local col 0..127
#pragma unroll
            for (int r = 0; r < 4; ++r) {
                const int lr = w * 16 + quad * 4 + r;  // local row 0..127
                Cst[lr * CST_STRIDE + lc] = f2bf(acc[c][r]);
            }
        }
    }
    __syncthreads();

    {
        const int cx = tid & 15;           // 16B chunk within 256B row-seg
        const int rbase = tid >> 4;        // 0..31
#pragma unroll
        for (int it = 0; it < 4; ++it) {
            const int lr = it * 32 + rbase;            // 0..127
            const int mrow = gb * 128 + lr;
            if (mrow < N_NODES) {
                uint4 v = *(const uint4*)&Cst[lr * CST_STRIDE + cx * 8];
                *(uint4*)(C + (size_t)mrow * NCOL + half * 128 + cx * 8) = v;
            }
        }
    }
}

// ---------------------------------------------------------------------------
// agg: (dir,head) sliced; WAVE-PER-(node,slice), two phases.
//  Phase A (lane = edge position 0..63): compute each edge weight ONCE
//    (w = exp(lrelu(esc[m]+base)), zero for lane >= deg), den via butterfly
//    reduce, pack (w bits, table byte-offset incl. head base) into LDS.
//  Phase B (lane = (el 0..3, col 0..15)): 8 edges per iter: 2 LDS reads
//    (w+off) -> 2x 8B table gathers -> shl+fma. No exp/esc/addressing in
//    the loop (agg is issue-bound, not fetch-bound: r1 vs r3 evidence).
//  Epilogue: 2-step shfl reduce over el, elu, float4 store by el==0.
//  __syncthreads() guards the LDS write->read edge (compiler-reorder safety).
// ---------------------------------------------------------------------------
__global__ __launch_bounds__(256) void agg_kernel(
    const int* __restrict__ cnt_t, const unsigned short* __restrict__ elist_t,
    const int* __restrict__ cnt_s, const unsigned short* __restrict__ elist_s,
    const float* __restrict__ ss1, const float* __restrict__ ss2,
    const float* __restrict__ tt1, const float* __restrict__ tt2,
    const unsigned short* __restrict__ s_bf, const unsigned short* __restrict__ t_bf,
    float* __restrict__ h_st, float* __restrict__ h_ts)
{
    const int b     = blockIdx.x;
    const int slice = b & 7;            // = XCD id (round-robin dispatch)
    const int dir   = slice >> 2;
    const int h     = slice & 3;
    const int wv    = threadIdx.x >> 6;
    const int lane  = threadIdx.x & 63;
    const int n     = (b >> 3) * 4 + wv;   // 5000*4 == 20000

    const int*            cnt   = dir ? cnt_s   : cnt_t;
    const unsigned short* list  = dir ? elist_s : elist_t;
    const unsigned short* table = dir ? t_bf    : s_bf;
    const float*          nsc   = dir ? ss2     : tt1;
    const float*          esc   = dir ? tt2     : ss1;
    float*                outp  = dir ? h_st    : h_ts;

    __shared__ uint2 wm[4][64];         // (w bits, byte-offset) per wave
    uint2* wmrow = wm[wv];

    int deg = cnt[n];
    if (deg > ELL_CAP) deg = ELL_CAP;

    // ---- Phase A: one weight per edge, computed once ----
    const int  mraw = list[n * ELL_CAP + lane];   // address always valid
    const bool act  = lane < deg;                 // value valid only when act
    const int  m    = act ? mraw : 0;
    const float ev   = esc[m * HEADS + h];
    const float base = nsc[n * HEADS + h];
    float w = act ? __expf(lrelu(ev + base)) : 0.f;

    float den = w;
#pragma unroll
    for (int msk = 1; msk < 64; msk <<= 1) den += __shfl_xor(den, msk, 64);
    const float inv = (den == 0.f) ? 1.f : 1.f / den;

    wmrow[lane] = make_uint2(__float_as_uint(w),
                             (unsigned)(m * (NCOL * 2) + h * 128));

    __syncthreads();   // LDS write -> cross-lane read ordering safety

    // ---- Phase B: aggregate, 8 edges/iter ----
    const int el   = lane >> 4;
    const int l15  = lane & 15;
    const unsigned cbyte = (unsigned)(l15 * 8);
    const char* tb = (const char*)table;

    float4 acc = make_float4(0.f, 0.f, 0.f, 0.f);
    for (int p = 0; p < deg; p += 8) {            // zero-padded: safe to 64
        uint2 a0 = wmrow[p + el];
        uint2 a1 = wmrow[p + 4 + el];
        float w0 = __uint_as_float(a0.x);
        float w1 = __uint_as_float(a1.x);
        ushort4 r0 = *(const ushort4*)(tb + (a0.y + cbyte));
        ushort4 r1 = *(const ushort4*)(tb + (a1.y + cbyte));
        acc.x += w0 * bf2f(r0.x) + w1 * bf2f(r1.x);
        acc.y += w0 * bf2f(r0.y) + w1 * bf2f(r1.y);
        acc.z += w0 * bf2f(r0.z) + w1 * bf2f(r1.z);
        acc.w += w0 * bf2f(r0.w) + w1 * bf2f(r1.w);
    }

#pragma unroll
    for (int msk = 16; msk < 64; msk <<= 1) {
        acc.x += __shfl_xor(acc.x, msk, 64);
        acc.y += __shfl_xor(acc.y, msk, 64);
        acc.z += __shfl_xor(acc.z, msk, 64);
        acc.w += __shfl_xor(acc.w, msk, 64);
    }

    if (el == 0) {
        float4 r;
        r.x = acc.x * inv; r.y = acc.y * inv;
        r.z = acc.z * inv; r.w = acc.w * inv;
        r.x = (r.x > 0.f) ? r.x : expm1f(r.x);
        r.y = (r.y > 0.f) ? r.y : expm1f(r.y);
        r.z = (r.z > 0.f) ? r.z : expm1f(r.z);
        r.w = (r.w > 0.f) ? r.w : expm1f(r.w);
        *(float4*)(outp + (size_t)n * NCOL + h * 64 + l15 * 4) = r;
    }
}

extern "C" void kernel_launch(void* const* d_in, const int* in_sizes, int n_in,
                              void* d_out, int out_size, void* d_ws, size_t ws_size,
                              hipStream_t stream)
{
    const float* input1 = (const float*)d_in[0];
    const float* input2 = (const float*)d_in[1];
    const float* Ws     = (const float*)d_in[2];
    const float* Wt     = (const float*)d_in[3];
    const float* a1     = (const float*)d_in[4];
    const float* a2     = (const float*)d_in[5];
    const int*   tgt    = (const int*)d_in[6];   // tgt_idx precedes src_idx
    const int*   src    = (const int*)d_in[7];

    float* out  = (float*)d_out;
    float* h_st = out;                            // [N, 256]
    float* h_ts = out + (size_t)N_NODES * NCOL;   // [N, 256]

    // workspace layout (~27.3 MB)
    unsigned short* s_bf = (unsigned short*)d_ws;             // 5,120,000 bf16
    unsigned short* t_bf = s_bf + (size_t)N_NODES * NCOL;     // 5,120,000 bf16
    unsigned short* Wsb  = t_bf + (size_t)N_NODES * NCOL;     // 65,536 bf16
    unsigned short* Wtb  = Wsb + 256 * 256;                   // 65,536 bf16
    float* ss1  = (float*)(Wtb + 256 * 256);                  // 80,000 f each
    float* ss2  = ss1 + N_NODES * HEADS;
    float* tt1  = ss2 + N_NODES * HEADS;
    float* tt2  = tt1 + N_NODES * HEADS;
    int*   cnt_t = (int*)(tt2 + N_NODES * HEADS);             // 20000
    int*   cnt_s = cnt_t + N_NODES;                           // 20000
    unsigned short* elist_t = (unsigned short*)(cnt_s + N_NODES);   // 20000*64 us
    unsigned short* elist_s = elist_t + (size_t)N_NODES * ELL_CAP;  // 20000*64 us

    // dispatch 1: W convert + counter zeroing
    prep_w_kernel<<<64, 256, 0, stream>>>(Ws, Wt, Wsb, Wtb, cnt_t);

    // dispatch 2: hybrid scatter + GEMM + fused dots (r8 verified)
    dim3 ggrid(SCAT_X + GEMM_GB * 2, 2);
    hybrid_kernel<<<ggrid, 512, 0, stream>>>(input1, Wsb, input2, Wtb,
                                             s_bf, t_bf, a1, a2,
                                             ss1, ss2, tt1, tt2,
                                             src, tgt, cnt_t, cnt_s,
                                             elist_t, elist_s);

    // dispatch 3: two-phase (dir,head)-sliced aggregation
    agg_kernel<<<AGG_BLOCKS, 256, 0, stream>>>(cnt_t, elist_t, cnt_s, elist_s,
                                               ss1, ss2, tt1, tt2, s_bf, t_bf,
                                               h_st, h_ts);
}

// Round 10
// 177.971 us; speedup vs baseline: 1.1329x; 1.1329x over previous
//
#include <hip/hip_runtime.h>
#include <math.h>

#define N_NODES 20000
#define N_EDGES 320000
#define IN_F 256
#define OUT_F 64
#define HEADS 4
#define NCOL 256            // HEADS*OUT_F
#define LRELU_ALPHA 0.1f
#define ELL_CAP 64          // max degree capacity; P(overflow) < 1e-13

#define SCAT_X 313                         // scatter blocks per y (512 thr, 1 edge/thread)
#define GEMM_GB 157                        // ceil(1250 row-groups / 8 waves)
#define CST_STRIDE 136                     // shorts per staged C row

typedef __attribute__((ext_vector_type(8))) short short8;
typedef __attribute__((ext_vector_type(4))) float floatx4;

__device__ __forceinline__ float lrelu(float x) {
    return x > 0.f ? x : LRELU_ALPHA * x;
}
__device__ __forceinline__ unsigned short f2bf(float f) {   // RNE f32->bf16
    unsigned int u = __float_as_uint(f);
    u = (u + 0x7FFF + ((u >> 16) & 1)) >> 16;
    return (unsigned short)u;
}
__device__ __forceinline__ float bf2f(unsigned short u) {
    return __uint_as_float(((unsigned int)u) << 16);
}

// ---------------------------------------------------------------------------
// prep_w (64 blocks x 256)  [verified r0-r9, byte-identical]
// ---------------------------------------------------------------------------
__global__ __launch_bounds__(256) void prep_w_kernel(
    const float* __restrict__ Ws, const float* __restrict__ Wt,
    unsigned short* __restrict__ Wsb, unsigned short* __restrict__ Wtb,
    int* __restrict__ cnt)   // cnt_t followed by cnt_s
{
    const int gid = blockIdx.x * 256 + threadIdx.x;   // [0, 16384)

    for (int i = gid; i < 2 * N_NODES; i += 16384) cnt[i] = 0;

    const int mat = gid >> 13;
    const int r   = gid & 8191;
    const int kc  = r >> 8;          // 0..31 (k-octet)
    const int c   = r & 255;
    const float* W    = mat ? Wt : Ws;
    unsigned short* O = mat ? Wtb : Wsb;
    const int h = c >> 6, j = c & 63;
    const int k0 = kc * 8;
    unsigned short v[8] __attribute__((aligned(16)));
#pragma unroll
    for (int i = 0; i < 8; ++i)
        v[i] = f2bf(W[(size_t)h * (IN_F * OUT_F) + (size_t)(k0 + i) * OUT_F + j]);
    *(uint4*)(O + (size_t)c * IN_F + k0) = *(const uint4*)v;
}

// ---------------------------------------------------------------------------
// hybrid: scatter + half-W-resident GEMM + fused dots + LDS-staged C write.
// [verified r8, byte-identical]
// ---------------------------------------------------------------------------
__global__ __launch_bounds__(512, 4) void hybrid_kernel(
    const float* __restrict__ A0, const unsigned short* __restrict__ Wb0,
    const float* __restrict__ A1, const unsigned short* __restrict__ Wb1,
    unsigned short* __restrict__ C0, unsigned short* __restrict__ C1,
    const float* __restrict__ a1, const float* __restrict__ a2,
    float* __restrict__ ss1, float* __restrict__ ss2,
    float* __restrict__ tt1, float* __restrict__ tt2,
    const int* __restrict__ src, const int* __restrict__ tgt,
    int* __restrict__ cnt_t, int* __restrict__ cnt_s,
    unsigned short* __restrict__ elist_t, unsigned short* __restrict__ elist_s)
{
    const int tid = threadIdx.x;

    __shared__ __align__(16) unsigned short Bl[128][264];   // 67,584 B

    if (blockIdx.x < SCAT_X) {
        // ---- scatter: one edge per thread ----
        const int e = ((int)blockIdx.y * SCAT_X + (int)blockIdx.x) * 512 + tid;
        if (e < N_EDGES) {
            const int s = src[e], t = tgt[e];
            const int p = atomicAdd(&cnt_t[t], 1);
            const int q = atomicAdd(&cnt_s[s], 1);
            if (p < ELL_CAP) elist_t[t * ELL_CAP + p] = (unsigned short)s;
            if (q < ELL_CAP) elist_s[s * ELL_CAP + q] = (unsigned short)t;
        }
        return;
    }

    // ---- GEMM + fused dots ----
    const int gx   = blockIdx.x - SCAT_X;
    const int half = gx & 1;
    const int gb   = gx >> 1;             // 0..156
    const float* A           = (blockIdx.y == 0) ? A0 : A1;
    const unsigned short* Wb = (blockIdx.y == 0) ? Wb0 : Wb1;
    unsigned short* C        = (blockIdx.y == 0) ? C0 : C1;

    for (int i = tid; i < 4096; i += 512) {
        const int n  = i >> 5;            // 0..127
        const int kc = (i & 31) << 3;     // k-offset in shorts
        *(uint4*)&Bl[n][kc] = *(const uint4*)(Wb + (size_t)(half * 128 + n) * IN_F + kc);
    }
    __syncthreads();

    const int lane = tid & 63;
    const int w    = tid >> 6;            // wave 0..7
    const int quad = lane >> 4;
    const int l15  = lane & 15;
    const int g    = gb * 8 + w;          // row group 0..1255
    const bool live = (g < 1250);

    floatx4 acc[8];
#pragma unroll
    for (int c = 0; c < 8; ++c) acc[c] = (floatx4){0.f, 0.f, 0.f, 0.f};

    if (live) {
        const float* arow = A + (size_t)(g * 16 + l15) * IN_F + quad * 8;

        // batch 1: kk = 0..3
        float4 ua[8];
#pragma unroll
        for (int kk = 0; kk < 4; ++kk) {
            ua[2 * kk]     = *(const float4*)(arow + kk * 32);
            ua[2 * kk + 1] = *(const float4*)(arow + kk * 32 + 4);
        }
        short8 af[4];
#pragma unroll
        for (int kk = 0; kk < 4; ++kk) {
            short8 t;
            t[0] = (short)f2bf(ua[2 * kk].x);     t[1] = (short)f2bf(ua[2 * kk].y);
            t[2] = (short)f2bf(ua[2 * kk].z);     t[3] = (short)f2bf(ua[2 * kk].w);
            t[4] = (short)f2bf(ua[2 * kk + 1].x); t[5] = (short)f2bf(ua[2 * kk + 1].y);
            t[6] = (short)f2bf(ua[2 * kk + 1].z); t[7] = (short)f2bf(ua[2 * kk + 1].w);
            af[kk] = t;
        }

        // batch 2 loads fly under batch-1 MFMAs
        float4 ub[8];
#pragma unroll
        for (int kk = 0; kk < 4; ++kk) {
            ub[2 * kk]     = *(const float4*)(arow + (kk + 4) * 32);
            ub[2 * kk + 1] = *(const float4*)(arow + (kk + 4) * 32 + 4);
        }

#pragma unroll
        for (int kk = 0; kk < 4; ++kk) {
#pragma unroll
            for (int c = 0; c < 8; ++c) {
                short8 bfrag = *(const short8*)&Bl[c * 16 + l15][kk * 32 + quad * 8];
                acc[c] = __builtin_amdgcn_mfma_f32_16x16x32_bf16(af[kk], bfrag, acc[c], 0, 0, 0);
            }
        }

#pragma unroll
        for (int kk = 0; kk < 4; ++kk) {
            short8 t;
            t[0] = (short)f2bf(ub[2 * kk].x);     t[1] = (short)f2bf(ub[2 * kk].y);
            t[2] = (short)f2bf(ub[2 * kk].z);     t[3] = (short)f2bf(ub[2 * kk].w);
            t[4] = (short)f2bf(ub[2 * kk + 1].x); t[5] = (short)f2bf(ub[2 * kk + 1].y);
            t[6] = (short)f2bf(ub[2 * kk + 1].z); t[7] = (short)f2bf(ub[2 * kk + 1].w);
            af[kk] = t;
        }
#pragma unroll
        for (int kk = 0; kk < 4; ++kk) {
#pragma unroll
            for (int c = 0; c < 8; ++c) {
                short8 bfrag = *(const short8*)&Bl[c * 16 + l15][(kk + 4) * 32 + quad * 8];
                acc[c] = __builtin_amdgcn_mfma_f32_16x16x32_bf16(af[kk], bfrag, acc[c], 0, 0, 0);
            }
        }

        // ---- fused dots (register-only; before barriers) ----
        const int off_aj = (blockIdx.y == 0) ? 0 : 64;
        float* o1 = (blockIdx.y == 0) ? ss1 : tt1;
        float* o2 = (blockIdx.y == 0) ? ss2 : tt2;

        float p1[2][4] = {{0.f,0.f,0.f,0.f},{0.f,0.f,0.f,0.f}};
        float p2[2][4] = {{0.f,0.f,0.f,0.f},{0.f,0.f,0.f,0.f}};
#pragma unroll
        for (int c = 0; c < 8; ++c) {
            const int hl = c >> 2;                       // local head 0..1
            const int hh = half * 2 + hl;
            const int jj = (c & 3) * 16 + l15;
            const float w1 = a1[hh * 128 + off_aj + jj];
            const float w2 = a2[hh * 128 + off_aj + jj];
#pragma unroll
            for (int r = 0; r < 4; ++r) {
                p1[hl][r] += acc[c][r] * w1;
                p2[hl][r] += acc[c][r] * w2;
            }
        }
#pragma unroll
        for (int m = 1; m < 16; m <<= 1) {
#pragma unroll
            for (int hl = 0; hl < 2; ++hl)
#pragma unroll
                for (int r = 0; r < 4; ++r) {
                    p1[hl][r] += __shfl_xor(p1[hl][r], m, 64);
                    p2[hl][r] += __shfl_xor(p2[hl][r], m, 64);
                }
        }
        if (l15 == 0) {
#pragma unroll
            for (int r = 0; r < 4; ++r) {
                const int m = g * 16 + quad * 4 + r;
#pragma unroll
                for (int hl = 0; hl < 2; ++hl) {
                    const int hh = half * 2 + hl;
                    o1[m * HEADS + hh] = p1[hl][r];
                    o2[m * HEADS + hh] = p2[hl][r];
                }
            }
        }
    }

    // ---- C write via LDS staging: full-line writebacks only ----
    __syncthreads();                       // all waves done reading Bl
    unsigned short* Cst = &Bl[0][0];       // reuse as [128][CST_STRIDE]

    if (live) {
#pragma unroll
        for (int c = 0; c < 8; ++c) {
            const int lc = c * 16 + l15;               // local col 0..127
#pragma unroll
            for (int r = 0; r < 4; ++r) {
                const int lr = w * 16 + quad * 4 + r;  // local row 0..127
                Cst[lr * CST_STRIDE + lc] = f2bf(acc[c][r]);
            }
        }
    }
    __syncthreads();

    {
        const int cx = tid & 15;           // 16B chunk within 256B row-seg
        const int rbase = tid >> 4;        // 0..31
#pragma unroll
        for (int it = 0; it < 4; ++it) {
            const int lr = it * 32 + rbase;            // 0..127
            const int mrow = gb * 128 + lr;
            if (mrow < N_NODES) {
                uint4 v = *(const uint4*)&Cst[lr * CST_STRIDE + cx * 8];
                *(uint4*)(C + (size_t)mrow * NCOL + half * 128 + cx * 8) = v;
            }
        }
    }
}

// ---------------------------------------------------------------------------
// agg: r1/r5 SKELETON (wave per (node,dir), lane covers (head,col), full
// 512B table row per edge) with the redundant-exp fix validated by r9:
//  Phase A (lane = edge slot): ONE float4 gather pulls all 4 head-scores
//    for that edge (esc rows are contiguous); 4 exps per lane per NODE
//    (vs 4 per lane per 4 EDGES in r1 = 16x redundant); (w, row-byte-off)
//    uint2 pairs stored to wave-private LDS.
//  Phase B: r1's 4-edge-unroll loop, exp chain replaced by one broadcast
//    ds_read_b64 per edge; den accumulated from the same reads (identical
//    within each 16-lane h-group, no butterfly).
// ---------------------------------------------------------------------------
__global__ __launch_bounds__(256) void agg_kernel(
    const int* __restrict__ cnt_t, const unsigned short* __restrict__ elist_t,
    const int* __restrict__ cnt_s, const unsigned short* __restrict__ elist_s,
    const float* __restrict__ ss1, const float* __restrict__ ss2,
    const float* __restrict__ tt1, const float* __restrict__ tt2,
    const unsigned short* __restrict__ s_bf, const unsigned short* __restrict__ t_bf,
    float* __restrict__ h_st, float* __restrict__ h_ts)
{
    const int b    = blockIdx.x;            // 0..9999
    const int dir  = b & 1;                 // = XCD parity
    const int wave = threadIdx.x >> 6;
    const int lane = threadIdx.x & 63;
    const int n    = (b >> 1) * 4 + wave;   // 5000*4 == 20000
    const int h    = lane >> 4;
    const int coff = lane * 4;

    const int*            cnt   = dir ? cnt_s   : cnt_t;
    const unsigned short* list  = dir ? elist_s : elist_t;
    const unsigned short* table = dir ? t_bf    : s_bf;
    const float*          nsc   = dir ? ss2     : tt1;
    const float*          esc   = dir ? tt2     : ss1;
    float*                outp  = dir ? h_st    : h_ts;

    __shared__ __align__(16) uint2 wm[4][64][4];   // [wave][edge][head], 8 KB

    int deg = cnt[n];
    if (deg > ELL_CAP) deg = ELL_CAP;
    const unsigned short* lp = list + n * ELL_CAP;

    // ---- Phase A: per-edge weights, each computed once ----
    {
        const int  mraw = lp[lane];               // address always valid
        const bool act  = lane < deg;
        const int  m    = act ? mraw : 0;
        const float4 e4 = *(const float4*)(esc + m * HEADS);   // 16B gather
        const float4 b4 = *(const float4*)(nsc + n * HEADS);   // broadcast
        const float w0 = act ? __expf(lrelu(e4.x + b4.x)) : 0.f;
        const float w1 = act ? __expf(lrelu(e4.y + b4.y)) : 0.f;
        const float w2 = act ? __expf(lrelu(e4.z + b4.z)) : 0.f;
        const float w3 = act ? __expf(lrelu(e4.w + b4.w)) : 0.f;
        const unsigned off = (unsigned)(m * (NCOL * 2));       // table row byte-off
        wm[wave][lane][0] = make_uint2(__float_as_uint(w0), off);
        wm[wave][lane][1] = make_uint2(__float_as_uint(w1), off);
        wm[wave][lane][2] = make_uint2(__float_as_uint(w2), off);
        wm[wave][lane][3] = make_uint2(__float_as_uint(w3), off);
    }

    __syncthreads();   // all threads reach this (no early returns)

    // ---- Phase B: aggregate (r1 loop, LDS weights) ----
    const uint2* wrow = &wm[wave][0][h];          // stride 32 B per edge
    const char*  tb   = (const char*)table;
    const unsigned cb = (unsigned)(coff * 2);     // lane byte col offset

    float4 acc = make_float4(0.f, 0.f, 0.f, 0.f);
    float den = 0.f;

    int p = 0;
    for (; p + 3 < deg; p += 4) {
        uint2 a0 = wrow[(p + 0) * 4];
        uint2 a1 = wrow[(p + 1) * 4];
        uint2 a2 = wrow[(p + 2) * 4];
        uint2 a3 = wrow[(p + 3) * 4];
        float w0 = __uint_as_float(a0.x);
        float w1 = __uint_as_float(a1.x);
        float w2 = __uint_as_float(a2.x);
        float w3 = __uint_as_float(a3.x);
        ushort4 r0 = *(const ushort4*)(tb + (a0.y + cb));
        ushort4 r1 = *(const ushort4*)(tb + (a1.y + cb));
        ushort4 r2 = *(const ushort4*)(tb + (a2.y + cb));
        ushort4 r3 = *(const ushort4*)(tb + (a3.y + cb));
        den += (w0 + w1) + (w2 + w3);
        acc.x += (w0 * bf2f(r0.x) + w1 * bf2f(r1.x)) + (w2 * bf2f(r2.x) + w3 * bf2f(r3.x));
        acc.y += (w0 * bf2f(r0.y) + w1 * bf2f(r1.y)) + (w2 * bf2f(r2.y) + w3 * bf2f(r3.y));
        acc.z += (w0 * bf2f(r0.z) + w1 * bf2f(r1.z)) + (w2 * bf2f(r2.z) + w3 * bf2f(r3.z));
        acc.w += (w0 * bf2f(r0.w) + w1 * bf2f(r1.w)) + (w2 * bf2f(r2.w) + w3 * bf2f(r3.w));
    }
    for (; p < deg; ++p) {
        uint2 a0 = wrow[p * 4];
        float w0 = __uint_as_float(a0.x);
        ushort4 r0 = *(const ushort4*)(tb + (a0.y + cb));
        den += w0;
        acc.x += w0 * bf2f(r0.x);
        acc.y += w0 * bf2f(r0.y);
        acc.z += w0 * bf2f(r0.z);
        acc.w += w0 * bf2f(r0.w);
    }

    if (den == 0.f) den = 1.f;
    float inv = 1.f / den;
    float4 r;
    r.x = acc.x * inv; r.y = acc.y * inv; r.z = acc.z * inv; r.w = acc.w * inv;
    r.x = (r.x > 0.f) ? r.x : expm1f(r.x);
    r.y = (r.y > 0.f) ? r.y : expm1f(r.y);
    r.z = (r.z > 0.f) ? r.z : expm1f(r.z);
    r.w = (r.w > 0.f) ? r.w : expm1f(r.w);
    *(float4*)(outp + (size_t)n * NCOL + coff) = r;
}

extern "C" void kernel_launch(void* const* d_in, const int* in_sizes, int n_in,
                              void* d_out, int out_size, void* d_ws, size_t ws_size,
                              hipStream_t stream)
{
    const float* input1 = (const float*)d_in[0];
    const float* input2 = (const float*)d_in[1];
    const float* Ws     = (const float*)d_in[2];
    const float* Wt     = (const float*)d_in[3];
    const float* a1     = (const float*)d_in[4];
    const float* a2     = (const float*)d_in[5];
    const int*   tgt    = (const int*)d_in[6];   // tgt_idx precedes src_idx
    const int*   src    = (const int*)d_in[7];

    float* out  = (float*)d_out;
    float* h_st = out;                            // [N, 256]
    float* h_ts = out + (size_t)N_NODES * NCOL;   // [N, 256]

    // workspace layout (~27.3 MB)
    unsigned short* s_bf = (unsigned short*)d_ws;             // 5,120,000 bf16
    unsigned short* t_bf = s_bf + (size_t)N_NODES * NCOL;     // 5,120,000 bf16
    unsigned short* Wsb  = t_bf + (size_t)N_NODES * NCOL;     // 65,536 bf16
    unsigned short* Wtb  = Wsb + 256 * 256;                   // 65,536 bf16
    float* ss1  = (float*)(Wtb + 256 * 256);                  // 80,000 f each
    float* ss2  = ss1 + N_NODES * HEADS;
    float* tt1  = ss2 + N_NODES * HEADS;
    float* tt2  = tt1 + N_NODES * HEADS;
    int*   cnt_t = (int*)(tt2 + N_NODES * HEADS);             // 20000
    int*   cnt_s = cnt_t + N_NODES;                           // 20000
    unsigned short* elist_t = (unsigned short*)(cnt_s + N_NODES);   // 20000*64 us
    unsigned short* elist_s = elist_t + (size_t)N_NODES * ELL_CAP;  // 20000*64 us

    // dispatch 1: W convert + counter zeroing
    prep_w_kernel<<<64, 256, 0, stream>>>(Ws, Wt, Wsb, Wtb, cnt_t);

    // dispatch 2: hybrid scatter + GEMM + fused dots (r8 verified)
    dim3 ggrid(SCAT_X + GEMM_GB * 2, 2);
    hybrid_kernel<<<ggrid, 512, 0, stream>>>(input1, Wsb, input2, Wtb,
                                             s_bf, t_bf, a1, a2,
                                             ss1, ss2, tt1, tt2,
                                             src, tgt, cnt_t, cnt_s,
                                             elist_t, elist_s);

    // dispatch 3: dir-parity aggregation, r1 skeleton + LDS weight table
    agg_kernel<<<10000, 256, 0, stream>>>(cnt_t, elist_t, cnt_s, elist_s,
                                          ss1, ss2, tt1, tt2, s_bf, t_bf,
                                          h_st, h_ts);
}